// Round 11
// baseline (399.572 us; speedup 1.0000x reference)
//
#include <hip/hip_runtime.h>
#include <hip/hip_bf16.h>
#include <math.h>

typedef unsigned short ush;
typedef __attribute__((ext_vector_type(8))) short frag16;   // 8 bf16 = 4 VGPRs
typedef __attribute__((ext_vector_type(4))) float f32x4;

#define S_   1024
#define H_   1024
#define NH_  16
#define D_   64
#define L_   9
#define MB_  (1048576ull)

__device__ __forceinline__ ush bf16_rne(float x) {
  unsigned int b = __float_as_uint(x);
  b += 0x7FFFu + ((b >> 16) & 1u);
  return (ush)(b >> 16);
}
__device__ __forceinline__ void split2(float x, ush& h, ush& l) {
  h = bf16_rne(x);
  l = bf16_rne(x - __uint_as_float((unsigned int)h << 16));
}

// ---------------------------------------------------------------------------
// Split + transpose 4 weights in one launch. W [k][n] fp32 -> WTh/WTl [n][k]
// bf16. Grid (16,16,4). (verified R10)
// ---------------------------------------------------------------------------
__global__ __launch_bounds__(256) void split_wT4(
    const float* W0, const float* W1, const float* W2, const float* W3,
    ush* h0, ush* l0, ush* h1, ush* l1, ush* h2, ush* l2, ush* h3, ush* l3) {
  __shared__ __align__(16) float Ls[64][68];
  const float* W = (blockIdx.z == 0) ? W0 : (blockIdx.z == 1) ? W1
                 : (blockIdx.z == 2) ? W2 : W3;
  ush* Th = (blockIdx.z == 0) ? h0 : (blockIdx.z == 1) ? h1
          : (blockIdx.z == 2) ? h2 : h3;
  ush* Tl = (blockIdx.z == 0) ? l0 : (blockIdx.z == 1) ? l1
          : (blockIdx.z == 2) ? l2 : l3;
  const int tid = threadIdx.x;
  const int n0 = blockIdx.x * 64, k0 = blockIdx.y * 64;
#pragma unroll
  for (int it = 0; it < 4; it++) {
    int flat = tid + 256 * it;
    int row = flat >> 4, nc = (flat & 15) * 4;
    *(float4*)&Ls[row][nc] = *(const float4*)&W[(size_t)(k0 + row) * 1024 + n0 + nc];
  }
  __syncthreads();
#pragma unroll
  for (int it = 0; it < 2; it++) {
    int flat = tid + 256 * it;
    int nrow = flat >> 3, kc = (flat & 7) * 8;
    ush hs[8], ls[8];
#pragma unroll
    for (int u = 0; u < 8; u++) split2(Ls[kc + u][nrow], hs[u], ls[u]);
    uint4 ph, pl;
    ph.x = hs[0] | ((unsigned)hs[1] << 16); ph.y = hs[2] | ((unsigned)hs[3] << 16);
    ph.z = hs[4] | ((unsigned)hs[5] << 16); ph.w = hs[6] | ((unsigned)hs[7] << 16);
    pl.x = ls[0] | ((unsigned)ls[1] << 16); pl.y = ls[2] | ((unsigned)ls[3] << 16);
    pl.z = ls[4] | ((unsigned)ls[5] << 16); pl.w = ls[6] | ((unsigned)ls[7] << 16);
    size_t o = (size_t)(n0 + nrow) * 1024 + k0 + kc;
    *(uint4*)&Th[o] = ph;
    *(uint4*)&Tl[o] = pl;
  }
}

// ---------------------------------------------------------------------------
// Split-bf16 MFMA GEMM, 128x128 tile, BK=32, 4 waves each owning 64x64
// (4x4 16x16x32 frag tiles, 3-term split => 48 MFMA per wave-k-step vs
// 16 frag b128 reads: 341 B/MFMA, 2x better than R10's 64-tile).
// B pre-split [n][k]. ASPLIT: 0 = A fp32 split in-loop; 1 = A pre-split.
// EP: 0 = hi/lo bf16 [bh][s][d] + bias (q,k); 1 = bf16 [bh][s][d] (v);
//     2 = fp32 [m][n] + bias + fp32 residual (o-proj).
// LDS 4 x 128x40 ush = 40,960 B.
// ---------------------------------------------------------------------------
template <int ASPLIT, int EP>
__global__ __launch_bounds__(256) void gemm128(
    const float* __restrict__ Af,
    const ush* __restrict__ Abh, const ush* __restrict__ Abl,
    const ush* __restrict__ Bgh, const ush* __restrict__ Bgl,
    const float* __restrict__ bias, const float* __restrict__ resid,
    float* __restrict__ outf, ush* __restrict__ oh, ush* __restrict__ ol) {
  __shared__ __align__(16) ush Ah[128][40], Al[128][40];
  __shared__ __align__(16) ush Bh[128][40], Bl[128][40];   // [n][k]
  const int tid = threadIdx.x;
  const int m0 = blockIdx.y * 128, n0 = blockIdx.x * 128;
  const int lane = tid & 63, wave = tid >> 6;
  const int wm = (wave >> 1) * 64, wn = (wave & 1) * 64;
  const int l15 = lane & 15, quad = lane >> 4;

  f32x4 acc[4][4];
#pragma unroll
  for (int i = 0; i < 4; i++)
#pragma unroll
    for (int j = 0; j < 4; j++) acc[i][j] = (f32x4){0.f, 0.f, 0.f, 0.f};

  for (int k0 = 0; k0 < 1024; k0 += 32) {
    if (ASPLIT == 0) {
      // A tile 128m x 32k fp32: 1024 float4s, 4/thread, split in-register
#pragma unroll
      for (int it = 0; it < 4; it++) {
        const int f4 = tid + 256 * it;
        const int arow = f4 >> 3, ak = (f4 & 7) * 4;
        float4 a4 = *(const float4*)&Af[(size_t)(m0 + arow) * 1024 + k0 + ak];
        const float aa[4] = {a4.x, a4.y, a4.z, a4.w};
        ush h[4], l[4];
#pragma unroll
        for (int c = 0; c < 4; c++) split2(aa[c], h[c], l[c]);
        *(uint2*)&Ah[arow][ak] =
            make_uint2((unsigned)h[0] | ((unsigned)h[1] << 16),
                       (unsigned)h[2] | ((unsigned)h[3] << 16));
        *(uint2*)&Al[arow][ak] =
            make_uint2((unsigned)l[0] | ((unsigned)l[1] << 16),
                       (unsigned)l[2] | ((unsigned)l[3] << 16));
      }
    } else {
      // A pre-split: 512 uint4 per array, 2/thread
#pragma unroll
      for (int it = 0; it < 2; it++) {
        const int u = tid + 256 * it;
        const int arow = u >> 2, akc = (u & 3) * 8;
        const size_t ga = (size_t)(m0 + arow) * 1024 + k0 + akc;
        *(uint4*)&Ah[arow][akc] = *(const uint4*)&Abh[ga];
        *(uint4*)&Al[arow][akc] = *(const uint4*)&Abl[ga];
      }
    }
#pragma unroll
    for (int it = 0; it < 2; it++) {
      const int u = tid + 256 * it;
      const int brow = u >> 2, bkc = (u & 3) * 8;
      const size_t gb = (size_t)(n0 + brow) * 1024 + k0 + bkc;
      *(uint4*)&Bh[brow][bkc] = *(const uint4*)&Bgh[gb];
      *(uint4*)&Bl[brow][bkc] = *(const uint4*)&Bgl[gb];
    }
    __syncthreads();

    frag16 a_h[4], a_l[4], b_h[4], b_l[4];
#pragma unroll
    for (int s = 0; s < 4; s++) {
      const int row = wm + s * 16 + l15;
      a_h[s] = *(const frag16*)&Ah[row][quad * 8];
      a_l[s] = *(const frag16*)&Al[row][quad * 8];
      const int col = wn + s * 16 + l15;
      b_h[s] = *(const frag16*)&Bh[col][quad * 8];
      b_l[s] = *(const frag16*)&Bl[col][quad * 8];
    }
#pragma unroll
    for (int mi = 0; mi < 4; mi++)
#pragma unroll
      for (int ni = 0; ni < 4; ni++) {
        acc[mi][ni] = __builtin_amdgcn_mfma_f32_16x16x32_bf16(
            a_h[mi], b_h[ni], acc[mi][ni], 0, 0, 0);
        acc[mi][ni] = __builtin_amdgcn_mfma_f32_16x16x32_bf16(
            a_h[mi], b_l[ni], acc[mi][ni], 0, 0, 0);
        acc[mi][ni] = __builtin_amdgcn_mfma_f32_16x16x32_bf16(
            a_l[mi], b_h[ni], acc[mi][ni], 0, 0, 0);
      }
    __syncthreads();
  }

#pragma unroll
  for (int mi = 0; mi < 4; mi++) {
    const int rbase = m0 + wm + mi * 16 + quad * 4;
#pragma unroll
    for (int ni = 0; ni < 4; ni++) {
      const int col = n0 + wn + ni * 16 + l15;
      const float bv = bias[col];
      const int hidx = col >> 6, d = col & 63;
#pragma unroll
      for (int r = 0; r < 4; r++) {
        const int m = rbase + r;
        float val = acc[mi][ni][r] + bv;
        if (EP == 2) {
          outf[(size_t)m * 1024 + col] = val + resid[(size_t)m * 1024 + col];
        } else {
          const int bb = m >> 10, ss = m & 1023;
          const size_t o = ((size_t)(bb * NH_ + hidx) * S_ + ss) * D_ + d;
          if (EP == 0) {
            ush hh, ll;
            split2(val, hh, ll);
            oh[o] = hh;
            ol[o] = ll;
          } else {
            oh[o] = bf16_rne(val);
          }
        }
      }
    }
  }
}

// ---------------------------------------------------------------------------
// V transpose: vbf [bh][s][d] bf16 -> vT [bh][d][s] bf16. (verified R10)
// ---------------------------------------------------------------------------
__global__ __launch_bounds__(256) void transpose_v(
    const ush* __restrict__ vbf, ush* __restrict__ vT) {
  __shared__ __align__(16) ush Ls[64][72];
  const int tid = threadIdx.x;
  const int s0 = blockIdx.x * 64, bh = blockIdx.y;
#pragma unroll
  for (int it = 0; it < 2; it++) {
    int flat = tid + 256 * it;
    int row = flat >> 3, dc = (flat & 7) * 8;
    *(uint4*)&Ls[row][dc] =
        *(const uint4*)&vbf[((size_t)bh * S_ + s0 + row) * D_ + dc];
  }
  __syncthreads();
#pragma unroll
  for (int it = 0; it < 2; it++) {
    int flat = tid + 256 * it;
    int drow = flat >> 3, sc = (flat & 7) * 8;
    ush v8[8];
#pragma unroll
    for (int u = 0; u < 8; u++) v8[u] = Ls[sc + u][drow];
    uint4 p;
    p.x = v8[0] | ((unsigned)v8[1] << 16); p.y = v8[2] | ((unsigned)v8[3] << 16);
    p.z = v8[4] | ((unsigned)v8[5] << 16); p.w = v8[6] | ((unsigned)v8[7] << 16);
    *(uint4*)&vT[((size_t)bh * D_ + drow) * S_ + s0 + sc] = p;
  }
}

// ---------------------------------------------------------------------------
// MFMA flash attention with FIXED-MAX softmax (M=20). Softmax is
// shift-invariant: exp(s-20)/sum(exp(s-20)) == exp(s-m)/sum(exp(s-m))
// exactly; scores are bounded ~[-102, +3] so exp(s-20) in [e^-122, e^-17]:
// no overflow (needs s>108), underflow only for terms < e^-80 relative.
// Removes ALL per-tile reductions (no shfl-max/sum, no alpha, no o-rescale);
// one deferred 16-lane shfl sum reduction at the end.
// ---------------------------------------------------------------------------
__global__ __launch_bounds__(256) void attn2(
    const ush* __restrict__ qh, const ush* __restrict__ ql,
    const ush* __restrict__ kh, const ush* __restrict__ kl,
    const ush* __restrict__ vT,
    ush* __restrict__ ch, ush* __restrict__ cl) {
  __shared__ __align__(16) ush Kh[64][72], Kl[64][72];
  __shared__ __align__(16) ush VTs[64][72];   // [d][j]
  __shared__ __align__(16) ush Pst[64][72];   // [m][j]
  const int tid = threadIdx.x;
  const int lane = tid & 63, wave = tid >> 6;
  const int l15 = lane & 15, quad = lane >> 4;
  const int w16 = wave * 16;
  const int bh = blockIdx.y;
  const int b = bh >> 4, h = bh & 15;
  const int q0 = blockIdx.x * 64;

  // ---- Q fragments straight from global (A-layout: m=l15, k=quad*8+j) ----
  const size_t qrow = ((size_t)bh * S_ + q0 + w16 + l15) * D_;
  frag16 a_h[2], a_l[2];
  a_h[0] = *(const frag16*)&qh[qrow + quad * 8];
  a_h[1] = *(const frag16*)&qh[qrow + 32 + quad * 8];
  a_l[0] = *(const frag16*)&ql[qrow + quad * 8];
  a_l[1] = *(const frag16*)&ql[qrow + 32 + quad * 8];

  f32x4 o[4];
  float lrow[4];
#pragma unroll
  for (int i = 0; i < 4; i++) {
    o[i] = (f32x4){0.f, 0.f, 0.f, 0.f};
    lrow[i] = 0.f;
  }

  const size_t kbase = (size_t)bh * S_ * D_;
  const size_t vbase = (size_t)bh * D_ * S_;
  for (int j0 = 0; j0 < S_; j0 += 64) {
    __syncthreads();   // prior tile's frag reads done
#pragma unroll
    for (int it = 0; it < 2; it++) {
      const int flat = tid + 256 * it;
      const int row = flat >> 3, dc = (flat & 7) * 8;
      const size_t gk = kbase + (size_t)(j0 + row) * D_ + dc;
      *(uint4*)&Kh[row][dc] = *(const uint4*)&kh[gk];
      *(uint4*)&Kl[row][dc] = *(const uint4*)&kl[gk];
      *(uint4*)&VTs[row][dc] =
          *(const uint4*)&vT[vbase + (size_t)row * S_ + j0 + dc];
    }
    __syncthreads();

    // ---- S = Q.K^T (3-term split) ----
    f32x4 c4[4];
#pragma unroll
    for (int nt = 0; nt < 4; nt++) c4[nt] = (f32x4){0.f, 0.f, 0.f, 0.f};
#pragma unroll
    for (int kk = 0; kk < 2; kk++) {
#pragma unroll
      for (int nt = 0; nt < 4; nt++) {
        frag16 bh_ = *(const frag16*)&Kh[nt * 16 + l15][kk * 32 + quad * 8];
        frag16 bl_ = *(const frag16*)&Kl[nt * 16 + l15][kk * 32 + quad * 8];
        c4[nt] = __builtin_amdgcn_mfma_f32_16x16x32_bf16(a_h[kk], bh_, c4[nt], 0, 0, 0);
        c4[nt] = __builtin_amdgcn_mfma_f32_16x16x32_bf16(a_l[kk], bh_, c4[nt], 0, 0, 0);
        c4[nt] = __builtin_amdgcn_mfma_f32_16x16x32_bf16(a_h[kk], bl_, c4[nt], 0, 0, 0);
      }
    }

    // ---- bias + fixed-max exp + P store (C-layout: row=quad*4+r, col=l15) --
    const bool far = (j0 >= q0 + 68) || (q0 >= j0 + 68);
#pragma unroll
    for (int r = 0; r < 4; r++) {
      const int qi = q0 + w16 + quad * 4 + r;
#pragma unroll
      for (int nt = 0; nt < 4; nt++) {
        const int jj = j0 + nt * 16 + l15;
        const float dist = fabsf((float)(qi - jj));
        const float pb = far ? 0.60653066f : __expf(-0.1f * fminf(dist, 5.0f));
        const float sv =
            __expf((c4[nt][r] + pb) * 0.125f - 0.1f * dist - 20.0f);
        lrow[r] += sv;
        Pst[w16 + quad * 4 + r][nt * 16 + l15] = bf16_rne(sv);
      }
    }

    // ---- PV (own rows only; same-wave LDS ordering, no barrier) ----
    frag16 pa[2];
#pragma unroll
    for (int kk = 0; kk < 2; kk++)
      pa[kk] = *(const frag16*)&Pst[w16 + l15][kk * 32 + quad * 8];
#pragma unroll
    for (int dt = 0; dt < 4; dt++) {
      frag16 vb0 = *(const frag16*)&VTs[dt * 16 + l15][quad * 8];
      frag16 vb1 = *(const frag16*)&VTs[dt * 16 + l15][32 + quad * 8];
      o[dt] = __builtin_amdgcn_mfma_f32_16x16x32_bf16(pa[0], vb0, o[dt], 0, 0, 0);
      o[dt] = __builtin_amdgcn_mfma_f32_16x16x32_bf16(pa[1], vb1, o[dt], 0, 0, 0);
    }
  }

  // ---- deferred row-sum reduction + normalize + write pre-split ctx ----
#pragma unroll
  for (int r = 0; r < 4; r++) {
#pragma unroll
    for (int off = 1; off < 16; off <<= 1) lrow[r] += __shfl_xor(lrow[r], off);
    const float inv = 1.0f / lrow[r];
    const size_t rowp =
        ((size_t)(b * S_ + q0 + w16 + quad * 4 + r)) * H_ + h * 64;
#pragma unroll
    for (int dt = 0; dt < 4; dt++) {
      ush hh, ll;
      split2(o[dt][r] * inv, hh, ll);
      ch[rowp + dt * 16 + l15] = hh;
      cl[rowp + dt * 16 + l15] = ll;
    }
  }
}

// ---------------------------------------------------------------------------
// Fused LayerNorm + span logits: one block per row. (verified R10)
// ---------------------------------------------------------------------------
__global__ __launch_bounds__(256) void ln_span(
    const float* __restrict__ y, const float* __restrict__ g,
    const float* __restrict__ bta, const float* __restrict__ Wsp,
    const float* __restrict__ bs, float* __restrict__ logits) {
  const int row = blockIdx.x;
  const int tid = threadIdx.x, lane = tid & 63, wave = tid >> 6;
  const float* yr = y + (size_t)row * 1024;
  float vals[4], s = 0.f, s2 = 0.f;
#pragma unroll
  for (int i = 0; i < 4; i++) {
    float t = yr[tid + i * 256];
    vals[i] = t; s += t; s2 += t * t;
  }
#pragma unroll
  for (int off = 32; off; off >>= 1) {
    s += __shfl_xor(s, off);
    s2 += __shfl_xor(s2, off);
  }
  __shared__ float red[8];
  __shared__ float red9[4][12];
  if (lane == 0) { red[wave] = s; red[4 + wave] = s2; }
  __syncthreads();
  s = red[0] + red[1] + red[2] + red[3];
  s2 = red[4] + red[5] + red[6] + red[7];
  const float mu = s * (1.0f / 1024.0f);
  const float var = s2 * (1.0f / 1024.0f) - mu * mu;
  const float inv = rsqrtf(var + 1e-5f);

  float lg[9];
#pragma unroll
  for (int l = 0; l < 9; l++) lg[l] = 0.f;
#pragma unroll
  for (int i = 0; i < 4; i++) {
    const int hh = tid + i * 256;
    const float yn = (vals[i] - mu) * inv * g[hh] + bta[hh];
#pragma unroll
    for (int l = 0; l < 9; l++) lg[l] += yn * Wsp[hh * 9 + l];
  }
#pragma unroll
  for (int l = 0; l < 9; l++) {
#pragma unroll
    for (int off = 32; off; off >>= 1) lg[l] += __shfl_xor(lg[l], off);
  }
  if (lane == 0) {
#pragma unroll
    for (int l = 0; l < 9; l++) red9[wave][l] = lg[l];
  }
  __syncthreads();
  if (tid < 9) {
    logits[(size_t)row * 9 + tid] =
        red9[0][tid] + red9[1][tid] + red9[2][tid] + red9[3][tid] + bs[tid];
  }
}

// ---------------------------------------------------------------------------
// Entity-bias adjustment + FP32 output. One thread per token.
// ---------------------------------------------------------------------------
__global__ __launch_bounds__(256) void final_kernel(
    const float* __restrict__ logits, const float* __restrict__ eb,
    float* __restrict__ out) {
  const int m = blockIdx.x * 256 + threadIdx.x;
  const int i = m & 1023;
  float cur[9];
#pragma unroll
  for (int l = 0; l < 9; l++) cur[l] = logits[(size_t)m * 9 + l];
  if (i > 0) {
    const float* prev = logits + (size_t)(m - 1) * 9;
    int am = 0;
    float best = prev[0];
#pragma unroll
    for (int l = 1; l < 9; l++) {
      float pv = prev[l];
      if (pv > best) { best = pv; am = l; }  // strict > == first-max argmax
    }
    if (am == 1) cur[2] += 2.0f * eb[2];
  }
#pragma unroll
  for (int l = 0; l < 9; l++) out[(size_t)m * 9 + l] = cur[l];
}

// ---------------------------------------------------------------------------
extern "C" void kernel_launch(void* const* d_in, const int* in_sizes, int n_in,
                              void* d_out, int out_size, void* d_ws, size_t ws_size,
                              hipStream_t stream) {
  const float* x    = (const float*)d_in[0];
  const float* Wq   = (const float*)d_in[1];
  const float* bq   = (const float*)d_in[2];
  const float* Wk   = (const float*)d_in[3];
  const float* bk   = (const float*)d_in[4];
  const float* Wv   = (const float*)d_in[5];
  const float* bv   = (const float*)d_in[6];
  const float* Wo   = (const float*)d_in[7];
  const float* bo   = (const float*)d_in[8];
  const float* ln_g = (const float*)d_in[9];
  const float* ln_b = (const float*)d_in[10];
  const float* Ws   = (const float*)d_in[11];
  const float* bs   = (const float*)d_in[12];
  const float* eb   = (const float*)d_in[13];
  float* out = (float*)d_out;       // output fp32 (verified R5)
  char* W8 = (char*)d_ws;

  // ---- ws layout (64 MB envelope, proven since R5) ----
  ush* WoT_h = (ush*)(W8 + 0 * MB_);
  ush* WoT_l = (ush*)(W8 + 2 * MB_);
  ush* WqT_h = (ush*)(W8 + 4 * MB_);
  ush* WqT_l = (ush*)(W8 + 6 * MB_);
  ush* WkT_h = (ush*)(W8 + 8 * MB_);
  ush* WkT_l = (ush*)(W8 + 10 * MB_);
  ush* WvT_h = (ush*)(W8 + 12 * MB_);
  ush* WvT_l = (ush*)(W8 + 14 * MB_);
  ush* qh    = (ush*)(W8 + 16 * MB_);
  ush* ql    = (ush*)(W8 + 24 * MB_);
  ush* kh    = (ush*)(W8 + 32 * MB_);
  ush* kl    = (ush*)(W8 + 40 * MB_);
  ush* vbf   = (ush*)(W8 + 48 * MB_);
  ush* vT    = (ush*)(W8 + 56 * MB_);
  // aliases (dead-slot reuse, ordering on one stream):
  ush*   ctxh   = (ush*)(W8 + 4 * MB_);    // over WqT/WkT_h (dead after QKV)
  ush*   ctxl   = (ush*)(W8 + 48 * MB_);   // over vbf (dead after transpose)
  float* y_ws   = (float*)(W8 + 32 * MB_); // over kh/kl (dead after attn)
  float* lg_ws  = (float*)(W8 + 56 * MB_); // over vT (dead after attn)

  split_wT4<<<dim3(16, 16, 4), 256, 0, stream>>>(
      Wq, Wk, Wv, Wo, WqT_h, WqT_l, WkT_h, WkT_l, WvT_h, WvT_l, WoT_h, WoT_l);

  dim3 g128(8, 32);
  gemm128<0, 0><<<g128, 256, 0, stream>>>(x, nullptr, nullptr, WqT_h, WqT_l,
                                          bq, nullptr, nullptr, qh, ql);
  gemm128<0, 0><<<g128, 256, 0, stream>>>(x, nullptr, nullptr, WkT_h, WkT_l,
                                          bk, nullptr, nullptr, kh, kl);
  gemm128<0, 1><<<g128, 256, 0, stream>>>(x, nullptr, nullptr, WvT_h, WvT_l,
                                          bv, nullptr, nullptr, vbf, nullptr);
  transpose_v<<<dim3(16, 64), 256, 0, stream>>>(vbf, vT);
  attn2<<<dim3(16, 64), 256, 0, stream>>>(qh, ql, kh, kl, vT, ctxh, ctxl);
  gemm128<1, 2><<<g128, 256, 0, stream>>>(nullptr, ctxh, ctxl, WoT_h, WoT_l,
                                          bo, x, y_ws, nullptr, nullptr);
  ln_span<<<4096, 256, 0, stream>>>(y_ws, ln_g, ln_b, Ws, bs, lg_ws);
  final_kernel<<<16, 256, 0, stream>>>(lg_ws, eb, out);
}

// Round 12
// 397.326 us; speedup vs baseline: 1.0057x; 1.0057x over previous
//
#include <hip/hip_runtime.h>
#include <hip/hip_bf16.h>
#include <math.h>

typedef unsigned short ush;
typedef __attribute__((ext_vector_type(8))) short frag16;   // 8 bf16 = 4 VGPRs
typedef __attribute__((ext_vector_type(4))) float f32x4;

#define S_   1024
#define H_   1024
#define NH_  16
#define D_   64
#define L_   9
#define MB_  (1048576ull)

__device__ __forceinline__ ush bf16_rne(float x) {
  unsigned int b = __float_as_uint(x);
  b += 0x7FFFu + ((b >> 16) & 1u);
  return (ush)(b >> 16);
}
__device__ __forceinline__ void split2(float x, ush& h, ush& l) {
  h = bf16_rne(x);
  l = bf16_rne(x - __uint_as_float((unsigned int)h << 16));
}

// ---------------------------------------------------------------------------
// Split + transpose 4 weights in one launch. W [k][n] fp32 -> WTh/WTl [n][k]
// bf16. Grid (16,16,4). (verified R10)
// ---------------------------------------------------------------------------
__global__ __launch_bounds__(256) void split_wT4(
    const float* W0, const float* W1, const float* W2, const float* W3,
    ush* h0, ush* l0, ush* h1, ush* l1, ush* h2, ush* l2, ush* h3, ush* l3) {
  __shared__ __align__(16) float Ls[64][68];
  const float* W = (blockIdx.z == 0) ? W0 : (blockIdx.z == 1) ? W1
                 : (blockIdx.z == 2) ? W2 : W3;
  ush* Th = (blockIdx.z == 0) ? h0 : (blockIdx.z == 1) ? h1
          : (blockIdx.z == 2) ? h2 : h3;
  ush* Tl = (blockIdx.z == 0) ? l0 : (blockIdx.z == 1) ? l1
          : (blockIdx.z == 2) ? l2 : l3;
  const int tid = threadIdx.x;
  const int n0 = blockIdx.x * 64, k0 = blockIdx.y * 64;
#pragma unroll
  for (int it = 0; it < 4; it++) {
    int flat = tid + 256 * it;
    int row = flat >> 4, nc = (flat & 15) * 4;
    *(float4*)&Ls[row][nc] = *(const float4*)&W[(size_t)(k0 + row) * 1024 + n0 + nc];
  }
  __syncthreads();
#pragma unroll
  for (int it = 0; it < 2; it++) {
    int flat = tid + 256 * it;
    int nrow = flat >> 3, kc = (flat & 7) * 8;
    ush hs[8], ls[8];
#pragma unroll
    for (int u = 0; u < 8; u++) split2(Ls[kc + u][nrow], hs[u], ls[u]);
    uint4 ph, pl;
    ph.x = hs[0] | ((unsigned)hs[1] << 16); ph.y = hs[2] | ((unsigned)hs[3] << 16);
    ph.z = hs[4] | ((unsigned)hs[5] << 16); ph.w = hs[6] | ((unsigned)hs[7] << 16);
    pl.x = ls[0] | ((unsigned)ls[1] << 16); pl.y = ls[2] | ((unsigned)ls[3] << 16);
    pl.z = ls[4] | ((unsigned)ls[5] << 16); pl.w = ls[6] | ((unsigned)ls[7] << 16);
    size_t o = (size_t)(n0 + nrow) * 1024 + k0 + kc;
    *(uint4*)&Th[o] = ph;
    *(uint4*)&Tl[o] = pl;
  }
}

// ---------------------------------------------------------------------------
// Split-bf16 MFMA GEMM, 64(M) x 128(N) tile, BK=32. Grid (8,64) = 512 blocks
// = 2 blocks/CU (fixes gemm128's 1-block/CU barrier serialization).
// 4 waves each own 32x64 (2x4 frag tiles): 12 frag b128 reads feed 24 MFMA
// (ratio 2.0 vs 64-tile's 1.5 -> less LDS-read-pipe pressure per MFMA).
// B pre-split [n][k]. ASPLIT: 0 = A fp32 split in-loop; 1 = A pre-split.
// EP: 0 = hi/lo bf16 [bh][s][d] + bias (q,k); 1 = bf16 [bh][s][d] (v);
//     2 = fp32 [m][n] + bias + fp32 residual (o-proj).
// LDS (64+128)*40*2*2 = 30,720 B.
// ---------------------------------------------------------------------------
template <int ASPLIT, int EP>
__global__ __launch_bounds__(256) void gemm_mn(
    const float* __restrict__ Af,
    const ush* __restrict__ Abh, const ush* __restrict__ Abl,
    const ush* __restrict__ Bgh, const ush* __restrict__ Bgl,
    const float* __restrict__ bias, const float* __restrict__ resid,
    float* __restrict__ outf, ush* __restrict__ oh, ush* __restrict__ ol) {
  __shared__ __align__(16) ush Ah[64][40], Al[64][40];
  __shared__ __align__(16) ush Bh[128][40], Bl[128][40];   // [n][k]
  const int tid = threadIdx.x;
  const int m0 = blockIdx.y * 64, n0 = blockIdx.x * 128;
  const int lane = tid & 63, wave = tid >> 6;
  const int wm = (wave >> 1) * 32, wn = (wave & 1) * 64;
  const int l15 = lane & 15, quad = lane >> 4;

  f32x4 acc[2][4];
#pragma unroll
  for (int i = 0; i < 2; i++)
#pragma unroll
    for (int j = 0; j < 4; j++) acc[i][j] = (f32x4){0.f, 0.f, 0.f, 0.f};

  for (int k0 = 0; k0 < 1024; k0 += 32) {
    if (ASPLIT == 0) {
      // A tile 64m x 32k fp32: 512 float4, 2/thread, split in-register (R10)
#pragma unroll
      for (int it = 0; it < 2; it++) {
        const int f4 = tid + 256 * it;
        const int arow = f4 >> 3, ak = (f4 & 7) * 4;
        float4 a4 = *(const float4*)&Af[(size_t)(m0 + arow) * 1024 + k0 + ak];
        const float aa[4] = {a4.x, a4.y, a4.z, a4.w};
        ush h[4], l[4];
#pragma unroll
        for (int c = 0; c < 4; c++) split2(aa[c], h[c], l[c]);
        *(uint2*)&Ah[arow][ak] =
            make_uint2((unsigned)h[0] | ((unsigned)h[1] << 16),
                       (unsigned)h[2] | ((unsigned)h[3] << 16));
        *(uint2*)&Al[arow][ak] =
            make_uint2((unsigned)l[0] | ((unsigned)l[1] << 16),
                       (unsigned)l[2] | ((unsigned)l[3] << 16));
      }
    } else {
      // A pre-split: 256 uint4 per array, 1/thread each
      const int arow = tid >> 2, akc = (tid & 3) * 8;
      const size_t ga = (size_t)(m0 + arow) * 1024 + k0 + akc;
      *(uint4*)&Ah[arow][akc] = *(const uint4*)&Abh[ga];
      *(uint4*)&Al[arow][akc] = *(const uint4*)&Abl[ga];
    }
    // B tile 128n x 32k pre-split: 512 uint4 per array, 2/thread each
#pragma unroll
    for (int it = 0; it < 2; it++) {
      const int u = tid + 256 * it;
      const int brow = u >> 2, bkc = (u & 3) * 8;
      const size_t gb = (size_t)(n0 + brow) * 1024 + k0 + bkc;
      *(uint4*)&Bh[brow][bkc] = *(const uint4*)&Bgh[gb];
      *(uint4*)&Bl[brow][bkc] = *(const uint4*)&Bgl[gb];
    }
    __syncthreads();

    frag16 a_h[2], a_l[2], b_h[4], b_l[4];
#pragma unroll
    for (int s = 0; s < 2; s++) {
      const int row = wm + s * 16 + l15;
      a_h[s] = *(const frag16*)&Ah[row][quad * 8];
      a_l[s] = *(const frag16*)&Al[row][quad * 8];
    }
#pragma unroll
    for (int t = 0; t < 4; t++) {
      const int col = wn + t * 16 + l15;
      b_h[t] = *(const frag16*)&Bh[col][quad * 8];
      b_l[t] = *(const frag16*)&Bl[col][quad * 8];
    }
#pragma unroll
    for (int mi = 0; mi < 2; mi++)
#pragma unroll
      for (int ni = 0; ni < 4; ni++) {
        acc[mi][ni] = __builtin_amdgcn_mfma_f32_16x16x32_bf16(
            a_h[mi], b_h[ni], acc[mi][ni], 0, 0, 0);
        acc[mi][ni] = __builtin_amdgcn_mfma_f32_16x16x32_bf16(
            a_h[mi], b_l[ni], acc[mi][ni], 0, 0, 0);
        acc[mi][ni] = __builtin_amdgcn_mfma_f32_16x16x32_bf16(
            a_l[mi], b_h[ni], acc[mi][ni], 0, 0, 0);
      }
    __syncthreads();
  }

#pragma unroll
  for (int mi = 0; mi < 2; mi++) {
    const int rbase = m0 + wm + mi * 16 + quad * 4;
#pragma unroll
    for (int ni = 0; ni < 4; ni++) {
      const int col = n0 + wn + ni * 16 + l15;
      const float bv = bias[col];
      const int hidx = col >> 6, d = col & 63;
#pragma unroll
      for (int r = 0; r < 4; r++) {
        const int m = rbase + r;
        float val = acc[mi][ni][r] + bv;
        if (EP == 2) {
          outf[(size_t)m * 1024 + col] = val + resid[(size_t)m * 1024 + col];
        } else {
          const int bb = m >> 10, ss = m & 1023;
          const size_t o = ((size_t)(bb * NH_ + hidx) * S_ + ss) * D_ + d;
          if (EP == 0) {
            ush hh, ll;
            split2(val, hh, ll);
            oh[o] = hh;
            ol[o] = ll;
          } else {
            oh[o] = bf16_rne(val);
          }
        }
      }
    }
  }
}

// ---------------------------------------------------------------------------
// V transpose: vbf [bh][s][d] bf16 -> vT [bh][d][s] bf16. (verified R10)
// ---------------------------------------------------------------------------
__global__ __launch_bounds__(256) void transpose_v(
    const ush* __restrict__ vbf, ush* __restrict__ vT) {
  __shared__ __align__(16) ush Ls[64][72];
  const int tid = threadIdx.x;
  const int s0 = blockIdx.x * 64, bh = blockIdx.y;
#pragma unroll
  for (int it = 0; it < 2; it++) {
    int flat = tid + 256 * it;
    int row = flat >> 3, dc = (flat & 7) * 8;
    *(uint4*)&Ls[row][dc] =
        *(const uint4*)&vbf[((size_t)bh * S_ + s0 + row) * D_ + dc];
  }
  __syncthreads();
#pragma unroll
  for (int it = 0; it < 2; it++) {
    int flat = tid + 256 * it;
    int drow = flat >> 3, sc = (flat & 7) * 8;
    ush v8[8];
#pragma unroll
    for (int u = 0; u < 8; u++) v8[u] = Ls[sc + u][drow];
    uint4 p;
    p.x = v8[0] | ((unsigned)v8[1] << 16); p.y = v8[2] | ((unsigned)v8[3] << 16);
    p.z = v8[4] | ((unsigned)v8[5] << 16); p.w = v8[6] | ((unsigned)v8[7] << 16);
    *(uint4*)&vT[((size_t)bh * D_ + drow) * S_ + s0 + sc] = p;
  }
}

// ---------------------------------------------------------------------------
// MFMA flash attention: fixed-max softmax (M=20, shift-invariant exact;
// scores bounded ~[-102,+3] -> exp in [e^-122, e^-17], no overflow, only
// negligible (<e^-80 rel) underflow) + SPLIT-P PV: P stored hi/lo bf16
// (error 2^-17, removes R11's dominant noise source that tie-flipped an
// argmax), 16 PV MFMAs. LDS 5*9216 = 46,080 B -> 3 blocks/CU.
// ---------------------------------------------------------------------------
__global__ __launch_bounds__(256) void attn2(
    const ush* __restrict__ qh, const ush* __restrict__ ql,
    const ush* __restrict__ kh, const ush* __restrict__ kl,
    const ush* __restrict__ vT,
    ush* __restrict__ ch, ush* __restrict__ cl) {
  __shared__ __align__(16) ush Kh[64][72], Kl[64][72];
  __shared__ __align__(16) ush VTs[64][72];    // [d][j]
  __shared__ __align__(16) ush Psth[64][72];   // [m][j] P hi
  __shared__ __align__(16) ush Pstl[64][72];   // [m][j] P lo
  const int tid = threadIdx.x;
  const int lane = tid & 63, wave = tid >> 6;
  const int l15 = lane & 15, quad = lane >> 4;
  const int w16 = wave * 16;
  const int bh = blockIdx.y;
  const int b = bh >> 4, h = bh & 15;
  const int q0 = blockIdx.x * 64;

  // ---- Q fragments straight from global (A-layout: m=l15, k=quad*8+j) ----
  const size_t qrow = ((size_t)bh * S_ + q0 + w16 + l15) * D_;
  frag16 a_h[2], a_l[2];
  a_h[0] = *(const frag16*)&qh[qrow + quad * 8];
  a_h[1] = *(const frag16*)&qh[qrow + 32 + quad * 8];
  a_l[0] = *(const frag16*)&ql[qrow + quad * 8];
  a_l[1] = *(const frag16*)&ql[qrow + 32 + quad * 8];

  f32x4 o[4];
  float lrow[4];
#pragma unroll
  for (int i = 0; i < 4; i++) {
    o[i] = (f32x4){0.f, 0.f, 0.f, 0.f};
    lrow[i] = 0.f;
  }

  const size_t kbase = (size_t)bh * S_ * D_;
  const size_t vbase = (size_t)bh * D_ * S_;
  for (int j0 = 0; j0 < S_; j0 += 64) {
    __syncthreads();   // prior tile's frag reads done
#pragma unroll
    for (int it = 0; it < 2; it++) {
      const int flat = tid + 256 * it;
      const int row = flat >> 3, dc = (flat & 7) * 8;
      const size_t gk = kbase + (size_t)(j0 + row) * D_ + dc;
      *(uint4*)&Kh[row][dc] = *(const uint4*)&kh[gk];
      *(uint4*)&Kl[row][dc] = *(const uint4*)&kl[gk];
      *(uint4*)&VTs[row][dc] =
          *(const uint4*)&vT[vbase + (size_t)row * S_ + j0 + dc];
    }
    __syncthreads();

    // ---- S = Q.K^T (3-term split) ----
    f32x4 c4[4];
#pragma unroll
    for (int nt = 0; nt < 4; nt++) c4[nt] = (f32x4){0.f, 0.f, 0.f, 0.f};
#pragma unroll
    for (int kk = 0; kk < 2; kk++) {
#pragma unroll
      for (int nt = 0; nt < 4; nt++) {
        frag16 bh_ = *(const frag16*)&Kh[nt * 16 + l15][kk * 32 + quad * 8];
        frag16 bl_ = *(const frag16*)&Kl[nt * 16 + l15][kk * 32 + quad * 8];
        c4[nt] = __builtin_amdgcn_mfma_f32_16x16x32_bf16(a_h[kk], bh_, c4[nt], 0, 0, 0);
        c4[nt] = __builtin_amdgcn_mfma_f32_16x16x32_bf16(a_l[kk], bh_, c4[nt], 0, 0, 0);
        c4[nt] = __builtin_amdgcn_mfma_f32_16x16x32_bf16(a_h[kk], bl_, c4[nt], 0, 0, 0);
      }
    }

    // ---- bias + fixed-max exp + split-P store (C-layout: row=quad*4+r) ----
    const bool far = (j0 >= q0 + 68) || (q0 >= j0 + 68);
#pragma unroll
    for (int r = 0; r < 4; r++) {
      const int qi = q0 + w16 + quad * 4 + r;
#pragma unroll
      for (int nt = 0; nt < 4; nt++) {
        const int jj = j0 + nt * 16 + l15;
        const float dist = fabsf((float)(qi - jj));
        const float pb = far ? 0.60653066f : __expf(-0.1f * fminf(dist, 5.0f));
        const float sv =
            __expf((c4[nt][r] + pb) * 0.125f - 0.1f * dist - 20.0f);
        lrow[r] += sv;
        ush hh, ll;
        split2(sv, hh, ll);
        Psth[w16 + quad * 4 + r][nt * 16 + l15] = hh;
        Pstl[w16 + quad * 4 + r][nt * 16 + l15] = ll;
      }
    }

    // ---- PV split (own rows only; same-wave LDS ordering, no barrier) ----
    frag16 pah[2], pal[2];
#pragma unroll
    for (int kk = 0; kk < 2; kk++) {
      pah[kk] = *(const frag16*)&Psth[w16 + l15][kk * 32 + quad * 8];
      pal[kk] = *(const frag16*)&Pstl[w16 + l15][kk * 32 + quad * 8];
    }
#pragma unroll
    for (int dt = 0; dt < 4; dt++) {
      frag16 vb0 = *(const frag16*)&VTs[dt * 16 + l15][quad * 8];
      frag16 vb1 = *(const frag16*)&VTs[dt * 16 + l15][32 + quad * 8];
      o[dt] = __builtin_amdgcn_mfma_f32_16x16x32_bf16(pah[0], vb0, o[dt], 0, 0, 0);
      o[dt] = __builtin_amdgcn_mfma_f32_16x16x32_bf16(pal[0], vb0, o[dt], 0, 0, 0);
      o[dt] = __builtin_amdgcn_mfma_f32_16x16x32_bf16(pah[1], vb1, o[dt], 0, 0, 0);
      o[dt] = __builtin_amdgcn_mfma_f32_16x16x32_bf16(pal[1], vb1, o[dt], 0, 0, 0);
    }
  }

  // ---- deferred row-sum reduction + normalize + write pre-split ctx ----
#pragma unroll
  for (int r = 0; r < 4; r++) {
#pragma unroll
    for (int off = 1; off < 16; off <<= 1) lrow[r] += __shfl_xor(lrow[r], off);
    const float inv = 1.0f / lrow[r];
    const size_t rowp =
        ((size_t)(b * S_ + q0 + w16 + quad * 4 + r)) * H_ + h * 64;
#pragma unroll
    for (int dt = 0; dt < 4; dt++) {
      ush hh, ll;
      split2(o[dt][r] * inv, hh, ll);
      ch[rowp + dt * 16 + l15] = hh;
      cl[rowp + dt * 16 + l15] = ll;
    }
  }
}

// ---------------------------------------------------------------------------
// Fused LayerNorm + span logits: one block per row. (verified R10)
// ---------------------------------------------------------------------------
__global__ __launch_bounds__(256) void ln_span(
    const float* __restrict__ y, const float* __restrict__ g,
    const float* __restrict__ bta, const float* __restrict__ Wsp,
    const float* __restrict__ bs, float* __restrict__ logits) {
  const int row = blockIdx.x;
  const int tid = threadIdx.x, lane = tid & 63, wave = tid >> 6;
  const float* yr = y + (size_t)row * 1024;
  float vals[4], s = 0.f, s2 = 0.f;
#pragma unroll
  for (int i = 0; i < 4; i++) {
    float t = yr[tid + i * 256];
    vals[i] = t; s += t; s2 += t * t;
  }
#pragma unroll
  for (int off = 32; off; off >>= 1) {
    s += __shfl_xor(s, off);
    s2 += __shfl_xor(s2, off);
  }
  __shared__ float red[8];
  __shared__ float red9[4][12];
  if (lane == 0) { red[wave] = s; red[4 + wave] = s2; }
  __syncthreads();
  s = red[0] + red[1] + red[2] + red[3];
  s2 = red[4] + red[5] + red[6] + red[7];
  const float mu = s * (1.0f / 1024.0f);
  const float var = s2 * (1.0f / 1024.0f) - mu * mu;
  const float inv = rsqrtf(var + 1e-5f);

  float lg[9];
#pragma unroll
  for (int l = 0; l < 9; l++) lg[l] = 0.f;
#pragma unroll
  for (int i = 0; i < 4; i++) {
    const int hh = tid + i * 256;
    const float yn = (vals[i] - mu) * inv * g[hh] + bta[hh];
#pragma unroll
    for (int l = 0; l < 9; l++) lg[l] += yn * Wsp[hh * 9 + l];
  }
#pragma unroll
  for (int l = 0; l < 9; l++) {
#pragma unroll
    for (int off = 32; off; off >>= 1) lg[l] += __shfl_xor(lg[l], off);
  }
  if (lane == 0) {
#pragma unroll
    for (int l = 0; l < 9; l++) red9[wave][l] = lg[l];
  }
  __syncthreads();
  if (tid < 9) {
    logits[(size_t)row * 9 + tid] =
        red9[0][tid] + red9[1][tid] + red9[2][tid] + red9[3][tid] + bs[tid];
  }
}

// ---------------------------------------------------------------------------
// Entity-bias adjustment + FP32 output. One thread per token.
// ---------------------------------------------------------------------------
__global__ __launch_bounds__(256) void final_kernel(
    const float* __restrict__ logits, const float* __restrict__ eb,
    float* __restrict__ out) {
  const int m = blockIdx.x * 256 + threadIdx.x;
  const int i = m & 1023;
  float cur[9];
#pragma unroll
  for (int l = 0; l < 9; l++) cur[l] = logits[(size_t)m * 9 + l];
  if (i > 0) {
    const float* prev = logits + (size_t)(m - 1) * 9;
    int am = 0;
    float best = prev[0];
#pragma unroll
    for (int l = 1; l < 9; l++) {
      float pv = prev[l];
      if (pv > best) { best = pv; am = l; }  // strict > == first-max argmax
    }
    if (am == 1) cur[2] += 2.0f * eb[2];
  }
#pragma unroll
  for (int l = 0; l < 9; l++) out[(size_t)m * 9 + l] = cur[l];
}

// ---------------------------------------------------------------------------
extern "C" void kernel_launch(void* const* d_in, const int* in_sizes, int n_in,
                              void* d_out, int out_size, void* d_ws, size_t ws_size,
                              hipStream_t stream) {
  const float* x    = (const float*)d_in[0];
  const float* Wq   = (const float*)d_in[1];
  const float* bq   = (const float*)d_in[2];
  const float* Wk   = (const float*)d_in[3];
  const float* bk   = (const float*)d_in[4];
  const float* Wv   = (const float*)d_in[5];
  const float* bv   = (const float*)d_in[6];
  const float* Wo   = (const float*)d_in[7];
  const float* bo   = (const float*)d_in[8];
  const float* ln_g = (const float*)d_in[9];
  const float* ln_b = (const float*)d_in[10];
  const float* Ws   = (const float*)d_in[11];
  const float* bs   = (const float*)d_in[12];
  const float* eb   = (const float*)d_in[13];
  float* out = (float*)d_out;       // output fp32 (verified R5)
  char* W8 = (char*)d_ws;

  // ---- ws layout (64 MB envelope, proven since R5) ----
  ush* WoT_h = (ush*)(W8 + 0 * MB_);
  ush* WoT_l = (ush*)(W8 + 2 * MB_);
  ush* WqT_h = (ush*)(W8 + 4 * MB_);
  ush* WqT_l = (ush*)(W8 + 6 * MB_);
  ush* WkT_h = (ush*)(W8 + 8 * MB_);
  ush* WkT_l = (ush*)(W8 + 10 * MB_);
  ush* WvT_h = (ush*)(W8 + 12 * MB_);
  ush* WvT_l = (ush*)(W8 + 14 * MB_);
  ush* qh    = (ush*)(W8 + 16 * MB_);
  ush* ql    = (ush*)(W8 + 24 * MB_);
  ush* kh    = (ush*)(W8 + 32 * MB_);
  ush* kl    = (ush*)(W8 + 40 * MB_);
  ush* vbf   = (ush*)(W8 + 48 * MB_);
  ush* vT    = (ush*)(W8 + 56 * MB_);
  // aliases (dead-slot reuse, ordering on one stream):
  ush*   ctxh   = (ush*)(W8 + 4 * MB_);    // over WqT/WkT_h (dead after QKV)
  ush*   ctxl   = (ush*)(W8 + 48 * MB_);   // over vbf (dead after transpose)
  float* y_ws   = (float*)(W8 + 32 * MB_); // over kh/kl (dead after attn)
  float* lg_ws  = (float*)(W8 + 56 * MB_); // over vT (dead after attn)

  split_wT4<<<dim3(16, 16, 4), 256, 0, stream>>>(
      Wq, Wk, Wv, Wo, WqT_h, WqT_l, WkT_h, WkT_l, WvT_h, WvT_l, WoT_h, WoT_l);

  dim3 g(8, 64);   // N-tiles x M-tiles -> 512 blocks = 2/CU
  gemm_mn<0, 0><<<g, 256, 0, stream>>>(x, nullptr, nullptr, WqT_h, WqT_l,
                                       bq, nullptr, nullptr, qh, ql);
  gemm_mn<0, 0><<<g, 256, 0, stream>>>(x, nullptr, nullptr, WkT_h, WkT_l,
                                       bk, nullptr, nullptr, kh, kl);
  gemm_mn<0, 1><<<g, 256, 0, stream>>>(x, nullptr, nullptr, WvT_h, WvT_l,
                                       bv, nullptr, nullptr, vbf, nullptr);
  transpose_v<<<dim3(16, 64), 256, 0, stream>>>(vbf, vT);
  attn2<<<dim3(16, 64), 256, 0, stream>>>(qh, ql, kh, kl, vT, ctxh, ctxl);
  gemm_mn<1, 2><<<g, 256, 0, stream>>>(nullptr, ctxh, ctxl, WoT_h, WoT_l,
                                       bo, x, y_ws, nullptr, nullptr);
  ln_span<<<4096, 256, 0, stream>>>(y_ws, ln_g, ln_b, Ws, bs, lg_ws);
  final_kernel<<<16, 256, 0, stream>>>(lg_ws, eb, out);
}

// Round 13
// 365.187 us; speedup vs baseline: 1.0942x; 1.0880x over previous
//
#include <hip/hip_runtime.h>
#include <hip/hip_bf16.h>
#include <math.h>

typedef unsigned short ush;
typedef __attribute__((ext_vector_type(8))) short frag16;   // 8 bf16 = 4 VGPRs
typedef __attribute__((ext_vector_type(4))) float f32x4;

#define S_   1024
#define H_   1024
#define NH_  16
#define D_   64
#define L_   9
#define MB_  (1048576ull)

__device__ __forceinline__ ush bf16_rne(float x) {
  unsigned int b = __float_as_uint(x);
  b += 0x7FFFu + ((b >> 16) & 1u);
  return (ush)(b >> 16);
}
__device__ __forceinline__ void split2(float x, ush& h, ush& l) {
  h = bf16_rne(x);
  l = bf16_rne(x - __uint_as_float((unsigned int)h << 16));
}

// ---------------------------------------------------------------------------
// Split + transpose 4 weights in one launch. W [k][n] fp32 -> WTh/WTl [n][k]
// bf16. Grid (16,16,4). (verified R10)
// ---------------------------------------------------------------------------
__global__ __launch_bounds__(256) void split_wT4(
    const float* W0, const float* W1, const float* W2, const float* W3,
    ush* h0, ush* l0, ush* h1, ush* l1, ush* h2, ush* l2, ush* h3, ush* l3) {
  __shared__ __align__(16) float Ls[64][68];
  const float* W = (blockIdx.z == 0) ? W0 : (blockIdx.z == 1) ? W1
                 : (blockIdx.z == 2) ? W2 : W3;
  ush* Th = (blockIdx.z == 0) ? h0 : (blockIdx.z == 1) ? h1
          : (blockIdx.z == 2) ? h2 : h3;
  ush* Tl = (blockIdx.z == 0) ? l0 : (blockIdx.z == 1) ? l1
          : (blockIdx.z == 2) ? l2 : l3;
  const int tid = threadIdx.x;
  const int n0 = blockIdx.x * 64, k0 = blockIdx.y * 64;
#pragma unroll
  for (int it = 0; it < 4; it++) {
    int flat = tid + 256 * it;
    int row = flat >> 4, nc = (flat & 15) * 4;
    *(float4*)&Ls[row][nc] = *(const float4*)&W[(size_t)(k0 + row) * 1024 + n0 + nc];
  }
  __syncthreads();
#pragma unroll
  for (int it = 0; it < 2; it++) {
    int flat = tid + 256 * it;
    int nrow = flat >> 3, kc = (flat & 7) * 8;
    ush hs[8], ls[8];
#pragma unroll
    for (int u = 0; u < 8; u++) split2(Ls[kc + u][nrow], hs[u], ls[u]);
    uint4 ph, pl;
    ph.x = hs[0] | ((unsigned)hs[1] << 16); ph.y = hs[2] | ((unsigned)hs[3] << 16);
    ph.z = hs[4] | ((unsigned)hs[5] << 16); ph.w = hs[6] | ((unsigned)hs[7] << 16);
    pl.x = ls[0] | ((unsigned)ls[1] << 16); pl.y = ls[2] | ((unsigned)ls[3] << 16);
    pl.z = ls[4] | ((unsigned)ls[5] << 16); pl.w = ls[6] | ((unsigned)ls[7] << 16);
    size_t o = (size_t)(n0 + nrow) * 1024 + k0 + kc;
    *(uint4*)&Th[o] = ph;
    *(uint4*)&Tl[o] = pl;
  }
}

// ---------------------------------------------------------------------------
// Pre-split x: fp32 [4096x1024] -> xh, xl bf16 row-major (same split2 bits
// the GEMM staging produced in-loop -> bitwise-neutral). Grid 2048.
// ---------------------------------------------------------------------------
__global__ __launch_bounds__(256) void split_x(
    const float* __restrict__ x, ush* __restrict__ xh, ush* __restrict__ xl) {
  const size_t i = ((size_t)blockIdx.x * 256 + threadIdx.x) * 8;
  float4 a = *(const float4*)&x[i];
  float4 b = *(const float4*)&x[i + 4];
  const float v[8] = {a.x, a.y, a.z, a.w, b.x, b.y, b.z, b.w};
  ush h[8], l[8];
#pragma unroll
  for (int u = 0; u < 8; u++) split2(v[u], h[u], l[u]);
  uint4 ph, pl;
  ph.x = h[0] | ((unsigned)h[1] << 16); ph.y = h[2] | ((unsigned)h[3] << 16);
  ph.z = h[4] | ((unsigned)h[5] << 16); ph.w = h[6] | ((unsigned)h[7] << 16);
  pl.x = l[0] | ((unsigned)l[1] << 16); pl.y = l[2] | ((unsigned)l[3] << 16);
  pl.z = l[4] | ((unsigned)l[5] << 16); pl.w = l[6] | ((unsigned)l[7] << 16);
  *(uint4*)&xh[i] = ph;
  *(uint4*)&xl[i] = pl;
}

// ---------------------------------------------------------------------------
// Split-bf16 MFMA GEMM, 64(M) x 128(N) tile, BK=32, copy-only staging
// (A and B both pre-split [.][k]-major). Grid (8,64) = 512 blocks = 2/CU.
// 4 waves each own 32x64 (2x4 frag tiles); 12 frag b128 reads feed 24 MFMA.
// EP: 0 = hi/lo bf16 [bh][s][d] + bias (q,k); 1 = bf16 [bh][s][d] (v);
//     2 = fp32 [m][n] + bias + fp32 residual (o-proj).
// LDS (64+128)*40*2*2 = 30,720 B.
// ---------------------------------------------------------------------------
template <int EP>
__global__ __launch_bounds__(256) void gemm_mn(
    const ush* __restrict__ Abh, const ush* __restrict__ Abl,
    const ush* __restrict__ Bgh, const ush* __restrict__ Bgl,
    const float* __restrict__ bias, const float* __restrict__ resid,
    float* __restrict__ outf, ush* __restrict__ oh, ush* __restrict__ ol) {
  __shared__ __align__(16) ush Ah[64][40], Al[64][40];
  __shared__ __align__(16) ush Bh[128][40], Bl[128][40];   // [n][k]
  const int tid = threadIdx.x;
  const int m0 = blockIdx.y * 64, n0 = blockIdx.x * 128;
  const int lane = tid & 63, wave = tid >> 6;
  const int wm = (wave >> 1) * 32, wn = (wave & 1) * 64;
  const int l15 = lane & 15, quad = lane >> 4;

  f32x4 acc[2][4];
#pragma unroll
  for (int i = 0; i < 2; i++)
#pragma unroll
    for (int j = 0; j < 4; j++) acc[i][j] = (f32x4){0.f, 0.f, 0.f, 0.f};

  for (int k0 = 0; k0 < 1024; k0 += 32) {
    {
      const int arow = tid >> 2, akc = (tid & 3) * 8;
      const size_t ga = (size_t)(m0 + arow) * 1024 + k0 + akc;
      *(uint4*)&Ah[arow][akc] = *(const uint4*)&Abh[ga];
      *(uint4*)&Al[arow][akc] = *(const uint4*)&Abl[ga];
    }
#pragma unroll
    for (int it = 0; it < 2; it++) {
      const int u = tid + 256 * it;
      const int brow = u >> 2, bkc = (u & 3) * 8;
      const size_t gb = (size_t)(n0 + brow) * 1024 + k0 + bkc;
      *(uint4*)&Bh[brow][bkc] = *(const uint4*)&Bgh[gb];
      *(uint4*)&Bl[brow][bkc] = *(const uint4*)&Bgl[gb];
    }
    __syncthreads();

    frag16 a_h[2], a_l[2], b_h[4], b_l[4];
#pragma unroll
    for (int s = 0; s < 2; s++) {
      const int row = wm + s * 16 + l15;
      a_h[s] = *(const frag16*)&Ah[row][quad * 8];
      a_l[s] = *(const frag16*)&Al[row][quad * 8];
    }
#pragma unroll
    for (int t = 0; t < 4; t++) {
      const int col = wn + t * 16 + l15;
      b_h[t] = *(const frag16*)&Bh[col][quad * 8];
      b_l[t] = *(const frag16*)&Bl[col][quad * 8];
    }
#pragma unroll
    for (int mi = 0; mi < 2; mi++)
#pragma unroll
      for (int ni = 0; ni < 4; ni++) {
        acc[mi][ni] = __builtin_amdgcn_mfma_f32_16x16x32_bf16(
            a_h[mi], b_h[ni], acc[mi][ni], 0, 0, 0);
        acc[mi][ni] = __builtin_amdgcn_mfma_f32_16x16x32_bf16(
            a_h[mi], b_l[ni], acc[mi][ni], 0, 0, 0);
        acc[mi][ni] = __builtin_amdgcn_mfma_f32_16x16x32_bf16(
            a_l[mi], b_h[ni], acc[mi][ni], 0, 0, 0);
      }
    __syncthreads();
  }

#pragma unroll
  for (int mi = 0; mi < 2; mi++) {
    const int rbase = m0 + wm + mi * 16 + quad * 4;
#pragma unroll
    for (int ni = 0; ni < 4; ni++) {
      const int col = n0 + wn + ni * 16 + l15;
      const float bv = bias[col];
      const int hidx = col >> 6, d = col & 63;
#pragma unroll
      for (int r = 0; r < 4; r++) {
        const int m = rbase + r;
        float val = acc[mi][ni][r] + bv;
        if (EP == 2) {
          outf[(size_t)m * 1024 + col] = val + resid[(size_t)m * 1024 + col];
        } else {
          const int bb = m >> 10, ss = m & 1023;
          const size_t o = ((size_t)(bb * NH_ + hidx) * S_ + ss) * D_ + d;
          if (EP == 0) {
            ush hh, ll;
            split2(val, hh, ll);
            oh[o] = hh;
            ol[o] = ll;
          } else {
            oh[o] = bf16_rne(val);
          }
        }
      }
    }
  }
}

// ---------------------------------------------------------------------------
// V transpose: vbf [bh][s][d] bf16 -> vT [bh][d][s] bf16. (verified R10)
// ---------------------------------------------------------------------------
__global__ __launch_bounds__(256) void transpose_v(
    const ush* __restrict__ vbf, ush* __restrict__ vT) {
  __shared__ __align__(16) ush Ls[64][72];
  const int tid = threadIdx.x;
  const int s0 = blockIdx.x * 64, bh = blockIdx.y;
#pragma unroll
  for (int it = 0; it < 2; it++) {
    int flat = tid + 256 * it;
    int row = flat >> 3, dc = (flat & 7) * 8;
    *(uint4*)&Ls[row][dc] =
        *(const uint4*)&vbf[((size_t)bh * S_ + s0 + row) * D_ + dc];
  }
  __syncthreads();
#pragma unroll
  for (int it = 0; it < 2; it++) {
    int flat = tid + 256 * it;
    int drow = flat >> 3, sc = (flat & 7) * 8;
    ush v8[8];
#pragma unroll
    for (int u = 0; u < 8; u++) v8[u] = Ls[sc + u][drow];
    uint4 p;
    p.x = v8[0] | ((unsigned)v8[1] << 16); p.y = v8[2] | ((unsigned)v8[3] << 16);
    p.z = v8[4] | ((unsigned)v8[5] << 16); p.w = v8[6] | ((unsigned)v8[7] << 16);
    *(uint4*)&vT[((size_t)bh * D_ + drow) * S_ + s0 + sc] = p;
  }
}

// ---------------------------------------------------------------------------
// MFMA flash attention, R11 version verbatim (78 us, deterministic pass):
// fixed-max softmax (M=20, shift-invariant exact; scores bounded -> exp in
// [e^-122, e^-17]), single-bf16 P, 8 PV MFMAs.
// LDS 4*9216 = 36,864 B -> 4 blocks/CU.
// ---------------------------------------------------------------------------
__global__ __launch_bounds__(256) void attn2(
    const ush* __restrict__ qh, const ush* __restrict__ ql,
    const ush* __restrict__ kh, const ush* __restrict__ kl,
    const ush* __restrict__ vT,
    ush* __restrict__ ch, ush* __restrict__ cl) {
  __shared__ __align__(16) ush Kh[64][72], Kl[64][72];
  __shared__ __align__(16) ush VTs[64][72];   // [d][j]
  __shared__ __align__(16) ush Pst[64][72];   // [m][j]
  const int tid = threadIdx.x;
  const int lane = tid & 63, wave = tid >> 6;
  const int l15 = lane & 15, quad = lane >> 4;
  const int w16 = wave * 16;
  const int bh = blockIdx.y;
  const int b = bh >> 4, h = bh & 15;
  const int q0 = blockIdx.x * 64;

  // ---- Q fragments straight from global (A-layout: m=l15, k=quad*8+j) ----
  const size_t qrow = ((size_t)bh * S_ + q0 + w16 + l15) * D_;
  frag16 a_h[2], a_l[2];
  a_h[0] = *(const frag16*)&qh[qrow + quad * 8];
  a_h[1] = *(const frag16*)&qh[qrow + 32 + quad * 8];
  a_l[0] = *(const frag16*)&ql[qrow + quad * 8];
  a_l[1] = *(const frag16*)&ql[qrow + 32 + quad * 8];

  f32x4 o[4];
  float lrow[4];
#pragma unroll
  for (int i = 0; i < 4; i++) {
    o[i] = (f32x4){0.f, 0.f, 0.f, 0.f};
    lrow[i] = 0.f;
  }

  const size_t kbase = (size_t)bh * S_ * D_;
  const size_t vbase = (size_t)bh * D_ * S_;
  for (int j0 = 0; j0 < S_; j0 += 64) {
    __syncthreads();   // prior tile's frag reads done
#pragma unroll
    for (int it = 0; it < 2; it++) {
      const int flat = tid + 256 * it;
      const int row = flat >> 3, dc = (flat & 7) * 8;
      const size_t gk = kbase + (size_t)(j0 + row) * D_ + dc;
      *(uint4*)&Kh[row][dc] = *(const uint4*)&kh[gk];
      *(uint4*)&Kl[row][dc] = *(const uint4*)&kl[gk];
      *(uint4*)&VTs[row][dc] =
          *(const uint4*)&vT[vbase + (size_t)row * S_ + j0 + dc];
    }
    __syncthreads();

    // ---- S = Q.K^T (3-term split) ----
    f32x4 c4[4];
#pragma unroll
    for (int nt = 0; nt < 4; nt++) c4[nt] = (f32x4){0.f, 0.f, 0.f, 0.f};
#pragma unroll
    for (int kk = 0; kk < 2; kk++) {
#pragma unroll
      for (int nt = 0; nt < 4; nt++) {
        frag16 bh_ = *(const frag16*)&Kh[nt * 16 + l15][kk * 32 + quad * 8];
        frag16 bl_ = *(const frag16*)&Kl[nt * 16 + l15][kk * 32 + quad * 8];
        c4[nt] = __builtin_amdgcn_mfma_f32_16x16x32_bf16(a_h[kk], bh_, c4[nt], 0, 0, 0);
        c4[nt] = __builtin_amdgcn_mfma_f32_16x16x32_bf16(a_l[kk], bh_, c4[nt], 0, 0, 0);
        c4[nt] = __builtin_amdgcn_mfma_f32_16x16x32_bf16(a_h[kk], bl_, c4[nt], 0, 0, 0);
      }
    }

    // ---- bias + fixed-max exp + P store (C-layout: row=quad*4+r) ----
    const bool far = (j0 >= q0 + 68) || (q0 >= j0 + 68);
#pragma unroll
    for (int r = 0; r < 4; r++) {
      const int qi = q0 + w16 + quad * 4 + r;
#pragma unroll
      for (int nt = 0; nt < 4; nt++) {
        const int jj = j0 + nt * 16 + l15;
        const float dist = fabsf((float)(qi - jj));
        const float pb = far ? 0.60653066f : __expf(-0.1f * fminf(dist, 5.0f));
        const float sv =
            __expf((c4[nt][r] + pb) * 0.125f - 0.1f * dist - 20.0f);
        lrow[r] += sv;
        Pst[w16 + quad * 4 + r][nt * 16 + l15] = bf16_rne(sv);
      }
    }

    // ---- PV (own rows only; same-wave LDS ordering, no barrier) ----
    frag16 pa[2];
#pragma unroll
    for (int kk = 0; kk < 2; kk++)
      pa[kk] = *(const frag16*)&Pst[w16 + l15][kk * 32 + quad * 8];
#pragma unroll
    for (int dt = 0; dt < 4; dt++) {
      frag16 vb0 = *(const frag16*)&VTs[dt * 16 + l15][quad * 8];
      frag16 vb1 = *(const frag16*)&VTs[dt * 16 + l15][32 + quad * 8];
      o[dt] = __builtin_amdgcn_mfma_f32_16x16x32_bf16(pa[0], vb0, o[dt], 0, 0, 0);
      o[dt] = __builtin_amdgcn_mfma_f32_16x16x32_bf16(pa[1], vb1, o[dt], 0, 0, 0);
    }
  }

  // ---- deferred row-sum reduction + normalize + write pre-split ctx ----
#pragma unroll
  for (int r = 0; r < 4; r++) {
#pragma unroll
    for (int off = 1; off < 16; off <<= 1) lrow[r] += __shfl_xor(lrow[r], off);
    const float inv = 1.0f / lrow[r];
    const size_t rowp =
        ((size_t)(b * S_ + q0 + w16 + quad * 4 + r)) * H_ + h * 64;
#pragma unroll
    for (int dt = 0; dt < 4; dt++) {
      ush hh, ll;
      split2(o[dt][r] * inv, hh, ll);
      ch[rowp + dt * 16 + l15] = hh;
      cl[rowp + dt * 16 + l15] = ll;
    }
  }
}

// ---------------------------------------------------------------------------
// Fused LayerNorm + span logits: one block per row. (verified R10)
// ---------------------------------------------------------------------------
__global__ __launch_bounds__(256) void ln_span(
    const float* __restrict__ y, const float* __restrict__ g,
    const float* __restrict__ bta, const float* __restrict__ Wsp,
    const float* __restrict__ bs, float* __restrict__ logits) {
  const int row = blockIdx.x;
  const int tid = threadIdx.x, lane = tid & 63, wave = tid >> 6;
  const float* yr = y + (size_t)row * 1024;
  float vals[4], s = 0.f, s2 = 0.f;
#pragma unroll
  for (int i = 0; i < 4; i++) {
    float t = yr[tid + i * 256];
    vals[i] = t; s += t; s2 += t * t;
  }
#pragma unroll
  for (int off = 32; off; off >>= 1) {
    s += __shfl_xor(s, off);
    s2 += __shfl_xor(s2, off);
  }
  __shared__ float red[8];
  __shared__ float red9[4][12];
  if (lane == 0) { red[wave] = s; red[4 + wave] = s2; }
  __syncthreads();
  s = red[0] + red[1] + red[2] + red[3];
  s2 = red[4] + red[5] + red[6] + red[7];
  const float mu = s * (1.0f / 1024.0f);
  const float var = s2 * (1.0f / 1024.0f) - mu * mu;
  const float inv = rsqrtf(var + 1e-5f);

  float lg[9];
#pragma unroll
  for (int l = 0; l < 9; l++) lg[l] = 0.f;
#pragma unroll
  for (int i = 0; i < 4; i++) {
    const int hh = tid + i * 256;
    const float yn = (vals[i] - mu) * inv * g[hh] + bta[hh];
#pragma unroll
    for (int l = 0; l < 9; l++) lg[l] += yn * Wsp[hh * 9 + l];
  }
#pragma unroll
  for (int l = 0; l < 9; l++) {
#pragma unroll
    for (int off = 32; off; off >>= 1) lg[l] += __shfl_xor(lg[l], off);
  }
  if (lane == 0) {
#pragma unroll
    for (int l = 0; l < 9; l++) red9[wave][l] = lg[l];
  }
  __syncthreads();
  if (tid < 9) {
    logits[(size_t)row * 9 + tid] =
        red9[0][tid] + red9[1][tid] + red9[2][tid] + red9[3][tid] + bs[tid];
  }
}

// ---------------------------------------------------------------------------
// Entity-bias adjustment + FP32 output. One thread per token.
// ---------------------------------------------------------------------------
__global__ __launch_bounds__(256) void final_kernel(
    const float* __restrict__ logits, const float* __restrict__ eb,
    float* __restrict__ out) {
  const int m = blockIdx.x * 256 + threadIdx.x;
  const int i = m & 1023;
  float cur[9];
#pragma unroll
  for (int l = 0; l < 9; l++) cur[l] = logits[(size_t)m * 9 + l];
  if (i > 0) {
    const float* prev = logits + (size_t)(m - 1) * 9;
    int am = 0;
    float best = prev[0];
#pragma unroll
    for (int l = 1; l < 9; l++) {
      float pv = prev[l];
      if (pv > best) { best = pv; am = l; }  // strict > == first-max argmax
    }
    if (am == 1) cur[2] += 2.0f * eb[2];
  }
#pragma unroll
  for (int l = 0; l < 9; l++) out[(size_t)m * 9 + l] = cur[l];
}

// ---------------------------------------------------------------------------
extern "C" void kernel_launch(void* const* d_in, const int* in_sizes, int n_in,
                              void* d_out, int out_size, void* d_ws, size_t ws_size,
                              hipStream_t stream) {
  const float* x    = (const float*)d_in[0];
  const float* Wq   = (const float*)d_in[1];
  const float* bq   = (const float*)d_in[2];
  const float* Wk   = (const float*)d_in[3];
  const float* bk   = (const float*)d_in[4];
  const float* Wv   = (const float*)d_in[5];
  const float* bv   = (const float*)d_in[6];
  const float* Wo   = (const float*)d_in[7];
  const float* bo   = (const float*)d_in[8];
  const float* ln_g = (const float*)d_in[9];
  const float* ln_b = (const float*)d_in[10];
  const float* Ws   = (const float*)d_in[11];
  const float* bs   = (const float*)d_in[12];
  const float* eb   = (const float*)d_in[13];
  float* out = (float*)d_out;       // output fp32 (verified R5)
  char* W8 = (char*)d_ws;

  // ---- ws layout, 64 MB envelope with phase-aliasing ----
  // [0,4):   WoT h+l            (alive until O-proj)
  // [4,8):   WqT h+l            (dead after q-gemm)
  // [8,12):  WkT h+l            (dead after k-gemm)
  // [12,16): WvT h+l            (dead after v-gemm)
  // [16,24): xh   [24,32): xl   (dead after v-gemm)
  // [32,40): qh   [40,48): ql   (dead after attn)
  // [48,56): kh   [56,64): kl   (dead after attn)
  ush* WoT_h = (ush*)(W8 + 0 * MB_);
  ush* WoT_l = (ush*)(W8 + 2 * MB_);
  ush* WqT_h = (ush*)(W8 + 4 * MB_);
  ush* WqT_l = (ush*)(W8 + 6 * MB_);
  ush* WkT_h = (ush*)(W8 + 8 * MB_);
  ush* WkT_l = (ush*)(W8 + 10 * MB_);
  ush* WvT_h = (ush*)(W8 + 12 * MB_);
  ush* WvT_l = (ush*)(W8 + 14 * MB_);
  ush* xh    = (ush*)(W8 + 16 * MB_);
  ush* xl    = (ush*)(W8 + 24 * MB_);
  ush* qh    = (ush*)(W8 + 32 * MB_);
  ush* ql    = (ush*)(W8 + 40 * MB_);
  ush* kh    = (ush*)(W8 + 48 * MB_);
  ush* kl    = (ush*)(W8 + 56 * MB_);
  // aliases:
  ush*   vbf  = (ush*)(W8 + 4 * MB_);    // over WqT+WkT (dead), 8 MB
  ush*   vT   = (ush*)(W8 + 16 * MB_);   // over xh (dead after v-gemm)
  ush*   ctxh = (ush*)(W8 + 24 * MB_);   // over xl (dead)
  ush*   ctxl = (ush*)(W8 + 4 * MB_);    // over vbf (dead after transpose)
  float* y_ws = (float*)(W8 + 32 * MB_); // over qh/ql (dead after attn)
  float* lg_ws = (float*)(W8 + 48 * MB_);// over kh (dead after attn)

  split_wT4<<<dim3(16, 16, 4), 256, 0, stream>>>(
      Wq, Wk, Wv, Wo, WqT_h, WqT_l, WkT_h, WkT_l, WvT_h, WvT_l, WoT_h, WoT_l);
  split_x<<<2048, 256, 0, stream>>>(x, xh, xl);

  dim3 g(8, 64);   // N-tiles x M-tiles -> 512 blocks = 2/CU
  gemm_mn<0><<<g, 256, 0, stream>>>(xh, xl, WqT_h, WqT_l,
                                    bq, nullptr, nullptr, qh, ql);
  gemm_mn<0><<<g, 256, 0, stream>>>(xh, xl, WkT_h, WkT_l,
                                    bk, nullptr, nullptr, kh, kl);
  gemm_mn<1><<<g, 256, 0, stream>>>(xh, xl, WvT_h, WvT_l,
                                    bv, nullptr, nullptr, vbf, nullptr);
  transpose_v<<<dim3(16, 64), 256, 0, stream>>>(vbf, vT);
  attn2<<<dim3(16, 64), 256, 0, stream>>>(qh, ql, kh, kl, vT, ctxh, ctxl);
  gemm_mn<2><<<g, 256, 0, stream>>>(ctxh, ctxl, WoT_h, WoT_l,
                                    bo, x, y_ws, nullptr, nullptr);
  ln_span<<<4096, 256, 0, stream>>>(y_ws, ln_g, ln_b, Ws, bs, lg_ws);
  final_kernel<<<16, 256, 0, stream>>>(lg_ws, eb, out);
}